// Round 9
// baseline (694.865 us; speedup 1.0000x reference)
//
#include <hip/hip_runtime.h>
#include <cstdint>

typedef uint32_t u32;

#define DEV static __device__ __forceinline__

DEV float gelu(float x){ return 0.5f * x * (1.0f + erff(x * 0.7071067811865475f)); }

// f32 weight workspace layout (element offsets)
enum : int {
  O_N1W=0, O_N1B=32, O_N2W=64, O_N2B=96, O_N3W=128, O_N3B=160, O_N4W=192, O_N4B=224,
  O_QKVW=256,            // 96x32
  O_QKVB=256+3072,       // 3328, 96
  O_PROJW=3424, O_PROJB=4448,
  O_KVW=4480, O_KVB=4512,
  O_GPW=4520, O_GPB=5544,
  O_SRW=5576, O_SRB=5832,
  O_NRMW=5834, O_NRMB=5838,
  O_M1W1=5842, O_M1B1=6866, O_M1W2=6898, O_M1B2=7922,
  O_M2W1=7954, O_M2B1=8978, O_M2W2=9010, O_M2B2=10034,
  O_TOTAL=10066
};

__global__ __launch_bounds__(256) void cpy_weights(float* __restrict__ ws,
  const float* n1w, const float* n1b, const float* n2w, const float* n2b,
  const float* n3w, const float* n3b, const float* n4w, const float* n4b,
  const float* qkvw, const float* qkvb, const float* projw, const float* projb,
  const float* kvw, const float* kvb, const float* gpw, const float* gpb,
  const float* srw, const float* srb, const float* nrmw, const float* nrmb,
  const float* m1w1, const float* m1b1, const float* m1w2, const float* m1b2,
  const float* m2w1, const float* m2b1, const float* m2w2, const float* m2b2)
{
  const int t  = blockIdx.x * blockDim.x + threadIdx.x;
  const int st = gridDim.x * blockDim.x;
#define CPY(p, off, len) { for (int i = t; i < (len); i += st) ws[(off) + i] = (p)[i]; }
  CPY(n1w, O_N1W, 32)  CPY(n1b, O_N1B, 32)  CPY(n2w, O_N2W, 32)  CPY(n2b, O_N2B, 32)
  CPY(n3w, O_N3W, 32)  CPY(n3b, O_N3B, 32)  CPY(n4w, O_N4W, 32)  CPY(n4b, O_N4B, 32)
  CPY(qkvw, O_QKVW, 3072) CPY(qkvb, O_QKVB, 96)
  CPY(projw, O_PROJW, 1024) CPY(projb, O_PROJB, 32)
  CPY(kvw, O_KVW, 32) CPY(kvb, O_KVB, 8)
  CPY(gpw, O_GPW, 1024) CPY(gpb, O_GPB, 32)
  CPY(srw, O_SRW, 256) CPY(srb, O_SRB, 2)
  CPY(nrmw, O_NRMW, 4) CPY(nrmb, O_NRMB, 4)
  CPY(m1w1, O_M1W1, 1024) CPY(m1b1, O_M1B1, 32) CPY(m1w2, O_M1W2, 1024) CPY(m1b2, O_M1B2, 32)
  CPY(m2w1, O_M2W1, 1024) CPY(m2b1, O_M2B1, 32) CPY(m2w2, O_M2W2, 1024) CPY(m2b2, O_M2B2, 32)
#undef CPY
}

DEV void ln32(const float* __restrict__ x, float* __restrict__ o,
              const float* __restrict__ W, int wo, int bo, float eps)
{
  float m = 0.f;
  #pragma unroll
  for (int i = 0; i < 32; i++) m += x[i];
  m *= 0.03125f;
  float v = 0.f;
  #pragma unroll
  for (int i = 0; i < 32; i++){ float d = x[i] - m; v += d * d; }
  v *= 0.03125f;
  const float rs = rsqrtf(v + eps);
  #pragma unroll
  for (int i = 0; i < 32; i++) o[i] = (x[i] - m) * rs * W[wo + i] + W[bo + i];
}

// produce: out[o] = act(bias[o] + sum_i in[i]*W[o*32+i])
template<bool GELU>
DEV void mm32r(const float* __restrict__ in, const float* __restrict__ W,
               int wOff, int bOff, float* __restrict__ out)
{
  #pragma unroll
  for (int o = 0; o < 32; o++){
    const float* wp = W + wOff + o * 32;
    float a = W[bOff + o];
    #pragma unroll
    for (int i = 0; i < 32; i++) a = fmaf(in[i], wp[i], a);
    out[o] = GELU ? gelu(a) : a;
  }
}

// accumulate: out[o] += bias[o] + sum_i in[i]*W[o*32+i]   (residual-fused, no temp array)
DEV void mm32r_add(const float* __restrict__ in, const float* __restrict__ W,
                   int wOff, int bOff, float* __restrict__ out)
{
  #pragma unroll
  for (int o = 0; o < 32; o++){
    const float* wp = W + wOff + o * 32;
    float a = W[bOff + o];
    #pragma unroll
    for (int i = 0; i < 32; i++) a = fmaf(in[i], wp[i], a);
    out[o] += a;
  }
}

__global__ __launch_bounds__(64, 2) void wtl_fwd(const float* __restrict__ Xin,
                                                 const float* __restrict__ W,
                                                 float* __restrict__ Out)
{
  // one wave per batch: LDS 8.7 KB/block; VGPR target <=128 (4 waves/SIMD), no scratch
  __shared__ float T[64][33];   // row buffer (33-pitch)
  __shared__ float XS[32];      // conv output xs[2][4][4]
  __shared__ float VB[32];      // v[2][4][4]

  const int lane = threadIdx.x;
  const int b    = blockIdx.x;
  const int rr   = lane;            // row index within batch: c*32 + h
  const int c    = rr >> 5;
  const int h    = rr & 31;
  const int h1   = h >> 3;          // 8-row block
  const int g2   = (h & 7) >> 1;    // row-pair within block
  const int par  = h & 1;           // parity within pair
  float* rowp = &T[rr][0];
  const float4* xp = reinterpret_cast<const float4*>(Xin + (size_t)b * 2048 + (size_t)rr * 32);

  float ln[32];

  // ================= stage A: group attention =================
  { // LN(x) straight into ln; xr NOT kept live through attention (reloaded at proj)
    float xr[32];
    #pragma unroll
    for (int i = 0; i < 8; i++){
      float4 u = xp[i];
      xr[i*4+0] = u.x; xr[i*4+1] = u.y; xr[i*4+2] = u.z; xr[i*4+3] = u.w;
    }
    ln32(xr, ln, W, O_N1W, O_N1B, 1e-6f);
  }
  {
    const float scale = 0.35355339059327373f;   // (IMG/NH)^-0.5 = 8^-0.5
    #pragma unroll 1
    for (int n = 0; n < 4; n++){
      float q[4][2], k[4][2], v[4][2];
      #pragma unroll
      for (int ch = 0; ch < 4; ch++){
        #pragma unroll
        for (int d = 0; d < 2; d++){
          const int cq = ch*24 + n*2 + d;       // q col; k = +8, v = +16
          const float* wq = W + O_QKVW + cq*32;
          float aq = W[O_QKVB + cq];
          float ak = W[O_QKVB + cq + 8];
          float av = W[O_QKVB + cq + 16];
          #pragma unroll
          for (int i = 0; i < 32; i++){
            const float x = ln[i];
            aq = fmaf(x, wq[i], aq);
            ak = fmaf(x, wq[256 + i], ak);
            av = fmaf(x, wq[512 + i], av);
          }
          q[ch][d] = aq; k[ch][d] = ak; v[ch][d] = av;
        }
      }
      // gather full seq (8) of k,v via partner-lane exchange (pair = rr^1)
      float ka[8][2], va[8][2];
      #pragma unroll
      for (int ch = 0; ch < 4; ch++){
        #pragma unroll
        for (int d = 0; d < 2; d++){
          const float kp = __shfl_xor(k[ch][d], 1, 64);
          const float vp = __shfl_xor(v[ch][d], 1, 64);
          ka[ch][d]   = par ? kp       : k[ch][d];
          ka[ch+4][d] = par ? k[ch][d] : kp;
          va[ch][d]   = par ? vp       : v[ch][d];
          va[ch+4][d] = par ? v[ch][d] : vp;
        }
      }
      const int h_out = (n >> 1) * 16 + ((h1 & 1) * 4 + g2) * 2 + (n & 1);
      const int row   = c * 32 + h_out;
      const int wbase = (h1 >> 1) * 16 + par * 8;
      #pragma unroll
      for (int si = 0; si < 4; si++){
        float sc[8];
        #pragma unroll
        for (int j = 0; j < 8; j++) sc[j] = (q[si][0]*ka[j][0] + q[si][1]*ka[j][1]) * scale;
        float mx = sc[0];
        #pragma unroll
        for (int j = 1; j < 8; j++) mx = fmaxf(mx, sc[j]);
        float s = 0.f;
        #pragma unroll
        for (int j = 0; j < 8; j++){ sc[j] = __expf(sc[j] - mx); s += sc[j]; }
        const float inv = 1.f / s;
        float o0 = 0.f, o1 = 0.f;
        #pragma unroll
        for (int j = 0; j < 8; j++){ o0 = fmaf(sc[j], va[j][0], o0); o1 = fmaf(sc[j], va[j][1], o1); }
        T[row][wbase + si*2 + 0] = o0 * inv;
        T[row][wbase + si*2 + 1] = o1 * inv;
      }
    }
  }
  __syncthreads();
  float xr[32];
  { // reload x (L2/L3-hot), then proj + residual accumulated in place
    #pragma unroll
    for (int i = 0; i < 8; i++){
      float4 u = xp[i];
      xr[i*4+0] = u.x; xr[i*4+1] = u.y; xr[i*4+2] = u.z; xr[i*4+3] = u.w;
    }
    float a[32];
    #pragma unroll
    for (int i = 0; i < 32; i++) a[i] = rowp[i];
    mm32r_add(a, W, O_PROJW, O_PROJB, xr);
  }

  // ================= stage B: MLP1 =================
  ln32(xr, ln, W, O_N2W, O_N2B, 1e-6f);
  {
    float hb[32];
    mm32r<true>(ln, W, O_M1W1, O_M1B1, hb);
    mm32r_add(hb, W, O_M1W2, O_M1B2, xr);
  }

  // ================= stage C: global attention (softmax over size-1 axis == broadcast of v) ====
  ln32(xr, ln, W, O_N3W, O_N3B, 1e-6f);
  __syncthreads();              // conv below reads all rows; ensure prior T reads (proj) done
  #pragma unroll
  for (int i = 0; i < 32; i++) rowp[i] = ln[i];
  __syncthreads();
  { // 8x8/stride-8 conv: lane = co*32 + ci*16 + i*4 + j; reduce over ci via shfl
    const int co = lane >> 5, ci = (lane >> 4) & 1, ii = (lane >> 2) & 3, jj = lane & 3;
    const float* wp = W + O_SRW + (co*2 + ci) * 64;
    float acc = 0.f;
    #pragma unroll 1
    for (int a8 = 0; a8 < 8; a8++){
      #pragma unroll
      for (int b8 = 0; b8 < 8; b8++)
        acc = fmaf(T[ci*32 + ii*8 + a8][jj*8 + b8], wp[a8*8 + b8], acc);
    }
    acc += __shfl_xor(acc, 16, 64);
    if (ci == 0) XS[co*16 + ii*4 + jj] = acc + W[O_SRB + co];
  }
  __syncthreads();
  if (lane < 32){ // LN(xs rows of 4, eps 1e-5) -> kv linear; keep only v rows (i = 2,3)
    const int cc = lane >> 4, i2 = (lane >> 2) & 3, j2 = lane & 3;
    const int ir = 2 + (i2 >> 1);
    const int oo = (i2 & 1) * 4 + j2;
    const float r0 = XS[cc*16 + ir*4 + 0], r1 = XS[cc*16 + ir*4 + 1],
                r2 = XS[cc*16 + ir*4 + 2], r3 = XS[cc*16 + ir*4 + 3];
    const float m  = (r0 + r1 + r2 + r3) * 0.25f;
    const float d0 = r0 - m, d1 = r1 - m, d2 = r2 - m, d3 = r3 - m;
    const float rs = rsqrtf((d0*d0 + d1*d1 + d2*d2 + d3*d3) * 0.25f + 1e-5f);
    const float l0 = d0*rs*W[O_NRMW+0] + W[O_NRMB+0];
    const float l1 = d1*rs*W[O_NRMW+1] + W[O_NRMB+1];
    const float l2 = d2*rs*W[O_NRMW+2] + W[O_NRMB+2];
    const float l3 = d3*rs*W[O_NRMW+3] + W[O_NRMB+3];
    VB[lane] = W[O_KVB+oo] + l0*W[O_KVW+oo*4+0] + l1*W[O_KVW+oo*4+1]
                           + l2*W[O_KVW+oo*4+2] + l3*W[O_KVW+oo*4+3];
  }
  __syncthreads();
  { // broadcast v into this row's 32 cols, project (residual-fused)
    const int u = (c << 2) | (h >> 3);
    float v4[4];
    #pragma unroll
    for (int dd = 0; dd < 4; dd++) v4[dd] = VB[(u & 1)*16 + (u >> 1)*4 + dd];
    float g[32];
    #pragma unroll
    for (int i = 0; i < 32; i++) g[i] = v4[i & 3];
    mm32r_add(g, W, O_GPW, O_GPB, xr);
  }

  // ================= stage D: MLP2 =================
  ln32(xr, ln, W, O_N4W, O_N4B, 1e-6f);
  {
    float hb[32];
    mm32r<true>(ln, W, O_M2W1, O_M2B1, hb);
    mm32r_add(hb, W, O_M2W2, O_M2B2, xr);
  }

  // ---- store (f32, float4 x8 = 128B) ----
  {
    float4* op = reinterpret_cast<float4*>(Out + (size_t)b * 2048 + (size_t)rr * 32);
    #pragma unroll
    for (int i = 0; i < 8; i++){
      float4 u;
      u.x = xr[i*4+0]; u.y = xr[i*4+1]; u.z = xr[i*4+2]; u.w = xr[i*4+3];
      op[i] = u;
    }
  }
}

extern "C" void kernel_launch(void* const* d_in, const int* in_sizes, int n_in,
                              void* d_out, int out_size, void* d_ws, size_t ws_size,
                              hipStream_t stream)
{
  (void)in_sizes; (void)n_in; (void)out_size; (void)ws_size;
  const float* x = (const float*)d_in[0];
  float* ws = (float*)d_ws;
  // d_in[13], d_in[14] (gl_q_w/b) are dead: softmax over a size-1 axis is identically 1.
  cpy_weights<<<16, 256, 0, stream>>>(ws,
    (const float*)d_in[1],  (const float*)d_in[2],  (const float*)d_in[3],  (const float*)d_in[4],
    (const float*)d_in[5],  (const float*)d_in[6],  (const float*)d_in[7],  (const float*)d_in[8],
    (const float*)d_in[9],  (const float*)d_in[10], (const float*)d_in[11], (const float*)d_in[12],
    (const float*)d_in[15], (const float*)d_in[16], (const float*)d_in[17], (const float*)d_in[18],
    (const float*)d_in[19], (const float*)d_in[20], (const float*)d_in[21], (const float*)d_in[22],
    (const float*)d_in[23], (const float*)d_in[24], (const float*)d_in[25], (const float*)d_in[26],
    (const float*)d_in[27], (const float*)d_in[28], (const float*)d_in[29], (const float*)d_in[30]);
  wtl_fwd<<<8192, 64, 0, stream>>>(x, ws, (float*)d_out);
}

// Round 13
// 462.543 us; speedup vs baseline: 1.5023x; 1.5023x over previous
//
#include <hip/hip_runtime.h>
#include <cstdint>

typedef uint32_t u32;

#define DEV static __device__ __forceinline__

DEV float gelu(float x){ return 0.5f * x * (1.0f + erff(x * 0.7071067811865475f)); }

// f32 weight workspace layout (element offsets)
enum : int {
  O_N1W=0, O_N1B=32, O_N2W=64, O_N2B=96, O_N3W=128, O_N3B=160, O_N4W=192, O_N4B=224,
  O_QKVW=256,            // 96x32
  O_QKVB=256+3072,       // 3328, 96
  O_PROJW=3424, O_PROJB=4448,
  O_KVW=4480, O_KVB=4512,
  O_GPW=4520, O_GPB=5544,
  O_SRW=5576, O_SRB=5832,
  O_NRMW=5834, O_NRMB=5838,
  O_M1W1=5842, O_M1B1=6866, O_M1W2=6898, O_M1B2=7922,
  O_M2W1=7954, O_M2B1=8978, O_M2W2=9010, O_M2B2=10034,
  O_TOTAL=10066
};

__global__ __launch_bounds__(256) void cpy_weights(float* __restrict__ ws,
  const float* n1w, const float* n1b, const float* n2w, const float* n2b,
  const float* n3w, const float* n3b, const float* n4w, const float* n4b,
  const float* qkvw, const float* qkvb, const float* projw, const float* projb,
  const float* kvw, const float* kvb, const float* gpw, const float* gpb,
  const float* srw, const float* srb, const float* nrmw, const float* nrmb,
  const float* m1w1, const float* m1b1, const float* m1w2, const float* m1b2,
  const float* m2w1, const float* m2b1, const float* m2w2, const float* m2b2)
{
  const int t  = blockIdx.x * blockDim.x + threadIdx.x;
  const int st = gridDim.x * blockDim.x;
#define CPY(p, off, len) { for (int i = t; i < (len); i += st) ws[(off) + i] = (p)[i]; }
  CPY(n1w, O_N1W, 32)  CPY(n1b, O_N1B, 32)  CPY(n2w, O_N2W, 32)  CPY(n2b, O_N2B, 32)
  CPY(n3w, O_N3W, 32)  CPY(n3b, O_N3B, 32)  CPY(n4w, O_N4W, 32)  CPY(n4b, O_N4B, 32)
  CPY(qkvw, O_QKVW, 3072) CPY(qkvb, O_QKVB, 96)
  CPY(projw, O_PROJW, 1024) CPY(projb, O_PROJB, 32)
  CPY(kvw, O_KVW, 32) CPY(kvb, O_KVB, 8)
  CPY(gpw, O_GPW, 1024) CPY(gpb, O_GPB, 32)
  CPY(srw, O_SRW, 256) CPY(srb, O_SRB, 2)
  CPY(nrmw, O_NRMW, 4) CPY(nrmb, O_NRMB, 4)
  CPY(m1w1, O_M1W1, 1024) CPY(m1b1, O_M1B1, 32) CPY(m1w2, O_M1W2, 1024) CPY(m1b2, O_M1B2, 32)
  CPY(m2w1, O_M2W1, 1024) CPY(m2b1, O_M2B1, 32) CPY(m2w2, O_M2W2, 1024) CPY(m2b2, O_M2B2, 32)
#undef CPY
}

DEV void ln32(const float* __restrict__ x, float* __restrict__ o,
              const float* __restrict__ W, int wo, int bo, float eps)
{
  float m = 0.f;
  #pragma unroll
  for (int i = 0; i < 32; i++) m += x[i];
  m *= 0.03125f;
  float v = 0.f;
  #pragma unroll
  for (int i = 0; i < 32; i++){ float d = x[i] - m; v += d * d; }
  v *= 0.03125f;
  const float rs = rsqrtf(v + eps);
  #pragma unroll
  for (int i = 0; i < 32; i++) o[i] = (x[i] - m) * rs * W[wo + i] + W[bo + i];
}

// produce: out[o] = act(bias[o] + sum_i in[i]*W[o*32+i])
template<bool GELU>
DEV void mm32r(const float* __restrict__ in, const float* __restrict__ W,
               int wOff, int bOff, float* __restrict__ out)
{
  #pragma unroll
  for (int o = 0; o < 32; o++){
    const float* wp = W + wOff + o * 32;
    float a = W[bOff + o];
    #pragma unroll
    for (int i = 0; i < 32; i++) a = fmaf(in[i], wp[i], a);
    out[o] = GELU ? gelu(a) : a;
  }
}

// accumulate: out[o] += bias[o] + sum_i in[i]*W[o*32+i]   (residual-fused, no temp array)
DEV void mm32r_add(const float* __restrict__ in, const float* __restrict__ W,
                   int wOff, int bOff, float* __restrict__ out)
{
  #pragma unroll
  for (int o = 0; o < 32; o++){
    const float* wp = W + wOff + o * 32;
    float a = W[bOff + o];
    #pragma unroll
    for (int i = 0; i < 32; i++) a = fmaf(in[i], wp[i], a);
    out[o] += a;
  }
}

// launch_bounds 2nd arg: empirically sets ACHIEVED waves/EU (r7: 4 -> 14.4 WG/CU, r9: 2 -> 7.6).
// 4 waves/EU -> 128-VGPR budget; current kernel's natural pressure is 88 (r9) -> no spill expected.
__global__ __launch_bounds__(64, 4) void wtl_fwd(const float* __restrict__ Xin,
                                                 const float* __restrict__ W,
                                                 float* __restrict__ Out)
{
  __shared__ float T[64][33];   // row buffer (33-pitch)
  __shared__ float XS[32];      // conv output xs[2][4][4]
  __shared__ float VB[32];      // v[2][4][4]

  const int lane = threadIdx.x;
  const int b    = blockIdx.x;
  const int rr   = lane;            // row index within batch: c*32 + h
  const int c    = rr >> 5;
  const int h    = rr & 31;
  const int h1   = h >> 3;          // 8-row block
  const int g2   = (h & 7) >> 1;    // row-pair within block
  const int par  = h & 1;           // parity within pair
  float* rowp = &T[rr][0];
  const float4* xp = reinterpret_cast<const float4*>(Xin + (size_t)b * 2048 + (size_t)rr * 32);

  float ln[32];

  // ================= stage A: group attention =================
  { // LN(x) straight into ln; xr NOT kept live through attention (reloaded at proj)
    float xr[32];
    #pragma unroll
    for (int i = 0; i < 8; i++){
      float4 u = xp[i];
      xr[i*4+0] = u.x; xr[i*4+1] = u.y; xr[i*4+2] = u.z; xr[i*4+3] = u.w;
    }
    ln32(xr, ln, W, O_N1W, O_N1B, 1e-6f);
  }
  {
    const float scale = 0.35355339059327373f;   // (IMG/NH)^-0.5 = 8^-0.5
    #pragma unroll 1
    for (int n = 0; n < 4; n++){
      float q[4][2], k[4][2], v[4][2];
      #pragma unroll
      for (int ch = 0; ch < 4; ch++){
        #pragma unroll
        for (int d = 0; d < 2; d++){
          const int cq = ch*24 + n*2 + d;       // q col; k = +8, v = +16
          const float* wq = W + O_QKVW + cq*32;
          float aq = W[O_QKVB + cq];
          float ak = W[O_QKVB + cq + 8];
          float av = W[O_QKVB + cq + 16];
          #pragma unroll
          for (int i = 0; i < 32; i++){
            const float x = ln[i];
            aq = fmaf(x, wq[i], aq);
            ak = fmaf(x, wq[256 + i], ak);
            av = fmaf(x, wq[512 + i], av);
          }
          q[ch][d] = aq; k[ch][d] = ak; v[ch][d] = av;
        }
      }
      // gather full seq (8) of k,v via partner-lane exchange (pair = rr^1)
      float ka[8][2], va[8][2];
      #pragma unroll
      for (int ch = 0; ch < 4; ch++){
        #pragma unroll
        for (int d = 0; d < 2; d++){
          const float kp = __shfl_xor(k[ch][d], 1, 64);
          const float vp = __shfl_xor(v[ch][d], 1, 64);
          ka[ch][d]   = par ? kp       : k[ch][d];
          ka[ch+4][d] = par ? k[ch][d] : kp;
          va[ch][d]   = par ? vp       : v[ch][d];
          va[ch+4][d] = par ? v[ch][d] : vp;
        }
      }
      const int h_out = (n >> 1) * 16 + ((h1 & 1) * 4 + g2) * 2 + (n & 1);
      const int row   = c * 32 + h_out;
      const int wbase = (h1 >> 1) * 16 + par * 8;
      #pragma unroll
      for (int si = 0; si < 4; si++){
        float sc[8];
        #pragma unroll
        for (int j = 0; j < 8; j++) sc[j] = (q[si][0]*ka[j][0] + q[si][1]*ka[j][1]) * scale;
        float mx = sc[0];
        #pragma unroll
        for (int j = 1; j < 8; j++) mx = fmaxf(mx, sc[j]);
        float s = 0.f;
        #pragma unroll
        for (int j = 0; j < 8; j++){ sc[j] = __expf(sc[j] - mx); s += sc[j]; }
        const float inv = 1.f / s;
        float o0 = 0.f, o1 = 0.f;
        #pragma unroll
        for (int j = 0; j < 8; j++){ o0 = fmaf(sc[j], va[j][0], o0); o1 = fmaf(sc[j], va[j][1], o1); }
        T[row][wbase + si*2 + 0] = o0 * inv;
        T[row][wbase + si*2 + 1] = o1 * inv;
      }
    }
  }
  __syncthreads();
  float xr[32];
  { // reload x (L2/L3-hot), then proj + residual accumulated in place
    #pragma unroll
    for (int i = 0; i < 8; i++){
      float4 u = xp[i];
      xr[i*4+0] = u.x; xr[i*4+1] = u.y; xr[i*4+2] = u.z; xr[i*4+3] = u.w;
    }
    float a[32];
    #pragma unroll
    for (int i = 0; i < 32; i++) a[i] = rowp[i];
    mm32r_add(a, W, O_PROJW, O_PROJB, xr);
  }

  // ================= stage B: MLP1 =================
  ln32(xr, ln, W, O_N2W, O_N2B, 1e-6f);
  {
    float hb[32];
    mm32r<true>(ln, W, O_M1W1, O_M1B1, hb);
    mm32r_add(hb, W, O_M1W2, O_M1B2, xr);
  }

  // ================= stage C: global attention (softmax over size-1 axis == broadcast of v) ====
  ln32(xr, ln, W, O_N3W, O_N3B, 1e-6f);
  __syncthreads();              // conv below reads all rows; ensure prior T reads (proj) done
  #pragma unroll
  for (int i = 0; i < 32; i++) rowp[i] = ln[i];
  __syncthreads();
  { // 8x8/stride-8 conv: lane = co*32 + ci*16 + i*4 + j; reduce over ci via shfl
    const int co = lane >> 5, ci = (lane >> 4) & 1, ii = (lane >> 2) & 3, jj = lane & 3;
    const float* wp = W + O_SRW + (co*2 + ci) * 64;
    float acc = 0.f;
    #pragma unroll 1
    for (int a8 = 0; a8 < 8; a8++){
      #pragma unroll
      for (int b8 = 0; b8 < 8; b8++)
        acc = fmaf(T[ci*32 + ii*8 + a8][jj*8 + b8], wp[a8*8 + b8], acc);
    }
    acc += __shfl_xor(acc, 16, 64);
    if (ci == 0) XS[co*16 + ii*4 + jj] = acc + W[O_SRB + co];
  }
  __syncthreads();
  if (lane < 32){ // LN(xs rows of 4, eps 1e-5) -> kv linear; keep only v rows (i = 2,3)
    const int cc = lane >> 4, i2 = (lane >> 2) & 3, j2 = lane & 3;
    const int ir = 2 + (i2 >> 1);
    const int oo = (i2 & 1) * 4 + j2;
    const float r0 = XS[cc*16 + ir*4 + 0], r1 = XS[cc*16 + ir*4 + 1],
                r2 = XS[cc*16 + ir*4 + 2], r3 = XS[cc*16 + ir*4 + 3];
    const float m  = (r0 + r1 + r2 + r3) * 0.25f;
    const float d0 = r0 - m, d1 = r1 - m, d2 = r2 - m, d3 = r3 - m;
    const float rs = rsqrtf((d0*d0 + d1*d1 + d2*d2 + d3*d3) * 0.25f + 1e-5f);
    const float l0 = d0*rs*W[O_NRMW+0] + W[O_NRMB+0];
    const float l1 = d1*rs*W[O_NRMW+1] + W[O_NRMB+1];
    const float l2 = d2*rs*W[O_NRMW+2] + W[O_NRMB+2];
    const float l3 = d3*rs*W[O_NRMW+3] + W[O_NRMB+3];
    VB[lane] = W[O_KVB+oo] + l0*W[O_KVW+oo*4+0] + l1*W[O_KVW+oo*4+1]
                           + l2*W[O_KVW+oo*4+2] + l3*W[O_KVW+oo*4+3];
  }
  __syncthreads();
  { // broadcast v into this row's 32 cols, project (residual-fused)
    const int u = (c << 2) | (h >> 3);
    float v4[4];
    #pragma unroll
    for (int dd = 0; dd < 4; dd++) v4[dd] = VB[(u & 1)*16 + (u >> 1)*4 + dd];
    float g[32];
    #pragma unroll
    for (int i = 0; i < 32; i++) g[i] = v4[i & 3];
    mm32r_add(g, W, O_GPW, O_GPB, xr);
  }

  // ================= stage D: MLP2 =================
  ln32(xr, ln, W, O_N4W, O_N4B, 1e-6f);
  {
    float hb[32];
    mm32r<true>(ln, W, O_M2W1, O_M2B1, hb);
    mm32r_add(hb, W, O_M2W2, O_M2B2, xr);
  }

  // ---- store (f32, float4 x8 = 128B) ----
  {
    float4* op = reinterpret_cast<float4*>(Out + (size_t)b * 2048 + (size_t)rr * 32);
    #pragma unroll
    for (int i = 0; i < 8; i++){
      float4 u;
      u.x = xr[i*4+0]; u.y = xr[i*4+1]; u.z = xr[i*4+2]; u.w = xr[i*4+3];
      op[i] = u;
    }
  }
}

extern "C" void kernel_launch(void* const* d_in, const int* in_sizes, int n_in,
                              void* d_out, int out_size, void* d_ws, size_t ws_size,
                              hipStream_t stream)
{
  (void)in_sizes; (void)n_in; (void)out_size; (void)ws_size;
  const float* x = (const float*)d_in[0];
  float* ws = (float*)d_ws;
  // d_in[13], d_in[14] (gl_q_w/b) are dead: softmax over a size-1 axis is identically 1.
  cpy_weights<<<16, 256, 0, stream>>>(ws,
    (const float*)d_in[1],  (const float*)d_in[2],  (const float*)d_in[3],  (const float*)d_in[4],
    (const float*)d_in[5],  (const float*)d_in[6],  (const float*)d_in[7],  (const float*)d_in[8],
    (const float*)d_in[9],  (const float*)d_in[10], (const float*)d_in[11], (const float*)d_in[12],
    (const float*)d_in[15], (const float*)d_in[16], (const float*)d_in[17], (const float*)d_in[18],
    (const float*)d_in[19], (const float*)d_in[20], (const float*)d_in[21], (const float*)d_in[22],
    (const float*)d_in[23], (const float*)d_in[24], (const float*)d_in[25], (const float*)d_in[26],
    (const float*)d_in[27], (const float*)d_in[28], (const float*)d_in[29], (const float*)d_in[30]);
  wtl_fwd<<<8192, 64, 0, stream>>>(x, ws, (float*)d_out);
}

// Round 15
// 461.458 us; speedup vs baseline: 1.5058x; 1.0024x over previous
//
#include <hip/hip_runtime.h>
#include <cstdint>

typedef uint32_t u32;

#define DEV static __device__ __forceinline__

DEV float gelu(float x){ return 0.5f * x * (1.0f + erff(x * 0.7071067811865475f)); }

// f32 weight workspace layout (element offsets)
enum : int {
  O_N1W=0, O_N1B=32, O_N2W=64, O_N2B=96, O_N3W=128, O_N3B=160, O_N4W=192, O_N4B=224,
  O_QKVW=256,            // 96x32
  O_QKVB=256+3072,       // 3328, 96
  O_PROJW=3424, O_PROJB=4448,
  O_KVW=4480, O_KVB=4512,
  O_GPW=4520, O_GPB=5544,
  O_SRW=5576, O_SRB=5832,
  O_NRMW=5834, O_NRMB=5838,
  O_M1W1=5842, O_M1B1=6866, O_M1W2=6898, O_M1B2=7922,
  O_M2W1=7954, O_M2B1=8978, O_M2W2=9010, O_M2B2=10034,
  O_TOTAL=10066
};

__global__ __launch_bounds__(256) void cpy_weights(float* __restrict__ ws,
  const float* n1w, const float* n1b, const float* n2w, const float* n2b,
  const float* n3w, const float* n3b, const float* n4w, const float* n4b,
  const float* qkvw, const float* qkvb, const float* projw, const float* projb,
  const float* kvw, const float* kvb, const float* gpw, const float* gpb,
  const float* srw, const float* srb, const float* nrmw, const float* nrmb,
  const float* m1w1, const float* m1b1, const float* m1w2, const float* m1b2,
  const float* m2w1, const float* m2b1, const float* m2w2, const float* m2b2)
{
  const int t  = blockIdx.x * blockDim.x + threadIdx.x;
  const int st = gridDim.x * blockDim.x;
#define CPY(p, off, len) { for (int i = t; i < (len); i += st) ws[(off) + i] = (p)[i]; }
  CPY(n1w, O_N1W, 32)  CPY(n1b, O_N1B, 32)  CPY(n2w, O_N2W, 32)  CPY(n2b, O_N2B, 32)
  CPY(n3w, O_N3W, 32)  CPY(n3b, O_N3B, 32)  CPY(n4w, O_N4W, 32)  CPY(n4b, O_N4B, 32)
  CPY(qkvw, O_QKVW, 3072) CPY(qkvb, O_QKVB, 96)
  CPY(projw, O_PROJW, 1024) CPY(projb, O_PROJB, 32)
  CPY(kvw, O_KVW, 32) CPY(kvb, O_KVB, 8)
  CPY(gpw, O_GPW, 1024) CPY(gpb, O_GPB, 32)
  CPY(srw, O_SRW, 256) CPY(srb, O_SRB, 2)
  CPY(nrmw, O_NRMW, 4) CPY(nrmb, O_NRMB, 4)
  CPY(m1w1, O_M1W1, 1024) CPY(m1b1, O_M1B1, 32) CPY(m1w2, O_M1W2, 1024) CPY(m1b2, O_M1B2, 32)
  CPY(m2w1, O_M2W1, 1024) CPY(m2b1, O_M2B1, 32) CPY(m2w2, O_M2W2, 1024) CPY(m2b2, O_M2B2, 32)
#undef CPY
}

DEV void ln32(const float* __restrict__ x, float* __restrict__ o,
              const float* __restrict__ W, int wo, int bo, float eps)
{
  float m = 0.f;
  #pragma unroll
  for (int i = 0; i < 32; i++) m += x[i];
  m *= 0.03125f;
  float v = 0.f;
  #pragma unroll
  for (int i = 0; i < 32; i++){ float d = x[i] - m; v += d * d; }
  v *= 0.03125f;
  const float rs = rsqrtf(v + eps);
  #pragma unroll
  for (int i = 0; i < 32; i++) o[i] = (x[i] - m) * rs * W[wo + i] + W[bo + i];
}

// produce: out[o] = act(bias[o] + sum_i in[i]*W[o*32+i])
template<bool GELU>
DEV void mm32r(const float* __restrict__ in, const float* __restrict__ W,
               int wOff, int bOff, float* __restrict__ out)
{
  #pragma unroll
  for (int o = 0; o < 32; o++){
    const float* wp = W + wOff + o * 32;
    float a = W[bOff + o];
    #pragma unroll
    for (int i = 0; i < 32; i++) a = fmaf(in[i], wp[i], a);
    out[o] = GELU ? gelu(a) : a;
  }
}

// accumulate: out[o] += bias[o] + sum_i in[i]*W[o*32+i]   (residual-fused, no temp array)
DEV void mm32r_add(const float* __restrict__ in, const float* __restrict__ W,
                   int wOff, int bOff, float* __restrict__ out)
{
  #pragma unroll
  for (int o = 0; o < 32; o++){
    const float* wp = W + wOff + o * 32;
    float a = W[bOff + o];
    #pragma unroll
    for (int i = 0; i < 32; i++) a = fmaf(in[i], wp[i], a);
    out[o] += a;
  }
}

// Occupancy model (r4/r7/r9/r13 measured): 64-thr WGs cap at ~4*arg waves/CU AND the 16-WG/CU
// HW limit -> r13 plateau 14.4 waves/CU. Multi-wave WGs escape the WG cap: 256-thr (4 batches),
// arg=4 -> 4 WG/CU x 4 waves = 16 waves/CU, VGPR budget 128 >= natural 88 -> no spill (vs r13's
// allocator squeeze to 64 + 280 MB scratch traffic). LDS 4x34.8KB = 139KB <= 160KB/CU.
__global__ __launch_bounds__(256, 4) void wtl_fwd(const float* __restrict__ Xin,
                                                  const float* __restrict__ W,
                                                  float* __restrict__ Out)
{
  __shared__ float T[4][64][33];   // per-wave row buffer (33-pitch)
  __shared__ float XS[4][32];      // per-wave conv output xs[2][4][4]
  __shared__ float VB[4][32];      // per-wave v[2][4][4]

  const int tid  = threadIdx.x;
  const int wid  = tid >> 6;
  const int lane = tid & 63;
  const int b    = blockIdx.x * 4 + wid;
  const int rr   = lane;            // row index within batch: c*32 + h
  const int c    = rr >> 5;
  const int h    = rr & 31;
  const int h1   = h >> 3;          // 8-row block
  const int g2   = (h & 7) >> 1;    // row-pair within block
  const int par  = h & 1;           // parity within pair
  float* rowp = &T[wid][rr][0];
  const float4* xp = reinterpret_cast<const float4*>(Xin + (size_t)b * 2048 + (size_t)rr * 32);

  float ln[32];

  // ================= stage A: group attention =================
  { // LN(x) straight into ln; xr NOT kept live through attention (reloaded at proj)
    float xr[32];
    #pragma unroll
    for (int i = 0; i < 8; i++){
      float4 u = xp[i];
      xr[i*4+0] = u.x; xr[i*4+1] = u.y; xr[i*4+2] = u.z; xr[i*4+3] = u.w;
    }
    ln32(xr, ln, W, O_N1W, O_N1B, 1e-6f);
  }
  {
    const float scale = 0.35355339059327373f;   // (IMG/NH)^-0.5 = 8^-0.5
    #pragma unroll 1
    for (int n = 0; n < 4; n++){
      float q[4][2], k[4][2], v[4][2];
      #pragma unroll
      for (int ch = 0; ch < 4; ch++){
        #pragma unroll
        for (int d = 0; d < 2; d++){
          const int cq = ch*24 + n*2 + d;       // q col; k = +8, v = +16
          const float* wq = W + O_QKVW + cq*32;
          float aq = W[O_QKVB + cq];
          float ak = W[O_QKVB + cq + 8];
          float av = W[O_QKVB + cq + 16];
          #pragma unroll
          for (int i = 0; i < 32; i++){
            const float x = ln[i];
            aq = fmaf(x, wq[i], aq);
            ak = fmaf(x, wq[256 + i], ak);
            av = fmaf(x, wq[512 + i], av);
          }
          q[ch][d] = aq; k[ch][d] = ak; v[ch][d] = av;
        }
      }
      // gather full seq (8) of k,v via partner-lane exchange (pair = rr^1)
      float ka[8][2], va[8][2];
      #pragma unroll
      for (int ch = 0; ch < 4; ch++){
        #pragma unroll
        for (int d = 0; d < 2; d++){
          const float kp = __shfl_xor(k[ch][d], 1, 64);
          const float vp = __shfl_xor(v[ch][d], 1, 64);
          ka[ch][d]   = par ? kp       : k[ch][d];
          ka[ch+4][d] = par ? k[ch][d] : kp;
          va[ch][d]   = par ? vp       : v[ch][d];
          va[ch+4][d] = par ? v[ch][d] : vp;
        }
      }
      const int h_out = (n >> 1) * 16 + ((h1 & 1) * 4 + g2) * 2 + (n & 1);
      const int row   = c * 32 + h_out;
      const int wbase = (h1 >> 1) * 16 + par * 8;
      #pragma unroll
      for (int si = 0; si < 4; si++){
        float sc[8];
        #pragma unroll
        for (int j = 0; j < 8; j++) sc[j] = (q[si][0]*ka[j][0] + q[si][1]*ka[j][1]) * scale;
        float mx = sc[0];
        #pragma unroll
        for (int j = 1; j < 8; j++) mx = fmaxf(mx, sc[j]);
        float s = 0.f;
        #pragma unroll
        for (int j = 0; j < 8; j++){ sc[j] = __expf(sc[j] - mx); s += sc[j]; }
        const float inv = 1.f / s;
        float o0 = 0.f, o1 = 0.f;
        #pragma unroll
        for (int j = 0; j < 8; j++){ o0 = fmaf(sc[j], va[j][0], o0); o1 = fmaf(sc[j], va[j][1], o1); }
        T[wid][row][wbase + si*2 + 0] = o0 * inv;
        T[wid][row][wbase + si*2 + 1] = o1 * inv;
      }
    }
  }
  __syncthreads();
  float xr[32];
  { // reload x (L2/L3-hot), then proj + residual accumulated in place
    #pragma unroll
    for (int i = 0; i < 8; i++){
      float4 u = xp[i];
      xr[i*4+0] = u.x; xr[i*4+1] = u.y; xr[i*4+2] = u.z; xr[i*4+3] = u.w;
    }
    float a[32];
    #pragma unroll
    for (int i = 0; i < 32; i++) a[i] = rowp[i];
    mm32r_add(a, W, O_PROJW, O_PROJB, xr);
  }

  // ================= stage B: MLP1 =================
  ln32(xr, ln, W, O_N2W, O_N2B, 1e-6f);
  {
    float hb[32];
    mm32r<true>(ln, W, O_M1W1, O_M1B1, hb);
    mm32r_add(hb, W, O_M1W2, O_M1B2, xr);
  }

  // ================= stage C: global attention (softmax over size-1 axis == broadcast of v) ====
  ln32(xr, ln, W, O_N3W, O_N3B, 1e-6f);
  __syncthreads();              // conv below reads all rows; ensure prior T reads (proj) done
  #pragma unroll
  for (int i = 0; i < 32; i++) rowp[i] = ln[i];
  __syncthreads();
  { // 8x8/stride-8 conv: lane = co*32 + ci*16 + i*4 + j; reduce over ci via shfl
    const int co = lane >> 5, ci = (lane >> 4) & 1, ii = (lane >> 2) & 3, jj = lane & 3;
    const float* wp = W + O_SRW + (co*2 + ci) * 64;
    float acc = 0.f;
    #pragma unroll 1
    for (int a8 = 0; a8 < 8; a8++){
      #pragma unroll
      for (int b8 = 0; b8 < 8; b8++)
        acc = fmaf(T[wid][ci*32 + ii*8 + a8][jj*8 + b8], wp[a8*8 + b8], acc);
    }
    acc += __shfl_xor(acc, 16, 64);
    if (ci == 0) XS[wid][co*16 + ii*4 + jj] = acc + W[O_SRB + co];
  }
  __syncthreads();
  if (lane < 32){ // LN(xs rows of 4, eps 1e-5) -> kv linear; keep only v rows (i = 2,3)
    const int cc = lane >> 4, i2 = (lane >> 2) & 3, j2 = lane & 3;
    const int ir = 2 + (i2 >> 1);
    const int oo = (i2 & 1) * 4 + j2;
    const float r0 = XS[wid][cc*16 + ir*4 + 0], r1 = XS[wid][cc*16 + ir*4 + 1],
                r2 = XS[wid][cc*16 + ir*4 + 2], r3 = XS[wid][cc*16 + ir*4 + 3];
    const float m  = (r0 + r1 + r2 + r3) * 0.25f;
    const float d0 = r0 - m, d1 = r1 - m, d2 = r2 - m, d3 = r3 - m;
    const float rs = rsqrtf((d0*d0 + d1*d1 + d2*d2 + d3*d3) * 0.25f + 1e-5f);
    const float l0 = d0*rs*W[O_NRMW+0] + W[O_NRMB+0];
    const float l1 = d1*rs*W[O_NRMW+1] + W[O_NRMB+1];
    const float l2 = d2*rs*W[O_NRMW+2] + W[O_NRMB+2];
    const float l3 = d3*rs*W[O_NRMW+3] + W[O_NRMB+3];
    VB[wid][lane] = W[O_KVB+oo] + l0*W[O_KVW+oo*4+0] + l1*W[O_KVW+oo*4+1]
                                + l2*W[O_KVW+oo*4+2] + l3*W[O_KVW+oo*4+3];
  }
  __syncthreads();
  { // broadcast v into this row's 32 cols, project (residual-fused)
    const int u = (c << 2) | (h >> 3);
    float v4[4];
    #pragma unroll
    for (int dd = 0; dd < 4; dd++) v4[dd] = VB[wid][(u & 1)*16 + (u >> 1)*4 + dd];
    float g[32];
    #pragma unroll
    for (int i = 0; i < 32; i++) g[i] = v4[i & 3];
    mm32r_add(g, W, O_GPW, O_GPB, xr);
  }

  // ================= stage D: MLP2 =================
  ln32(xr, ln, W, O_N4W, O_N4B, 1e-6f);
  {
    float hb[32];
    mm32r<true>(ln, W, O_M2W1, O_M2B1, hb);
    mm32r_add(hb, W, O_M2W2, O_M2B2, xr);
  }

  // ---- store (f32, float4 x8 = 128B) ----
  {
    float4* op = reinterpret_cast<float4*>(Out + (size_t)b * 2048 + (size_t)rr * 32);
    #pragma unroll
    for (int i = 0; i < 8; i++){
      float4 u;
      u.x = xr[i*4+0]; u.y = xr[i*4+1]; u.z = xr[i*4+2]; u.w = xr[i*4+3];
      op[i] = u;
    }
  }
}

extern "C" void kernel_launch(void* const* d_in, const int* in_sizes, int n_in,
                              void* d_out, int out_size, void* d_ws, size_t ws_size,
                              hipStream_t stream)
{
  (void)in_sizes; (void)n_in; (void)out_size; (void)ws_size;
  const float* x = (const float*)d_in[0];
  float* ws = (float*)d_ws;
  // d_in[13], d_in[14] (gl_q_w/b) are dead: softmax over a size-1 axis is identically 1.
  cpy_weights<<<16, 256, 0, stream>>>(ws,
    (const float*)d_in[1],  (const float*)d_in[2],  (const float*)d_in[3],  (const float*)d_in[4],
    (const float*)d_in[5],  (const float*)d_in[6],  (const float*)d_in[7],  (const float*)d_in[8],
    (const float*)d_in[9],  (const float*)d_in[10], (const float*)d_in[11], (const float*)d_in[12],
    (const float*)d_in[15], (const float*)d_in[16], (const float*)d_in[17], (const float*)d_in[18],
    (const float*)d_in[19], (const float*)d_in[20], (const float*)d_in[21], (const float*)d_in[22],
    (const float*)d_in[23], (const float*)d_in[24], (const float*)d_in[25], (const float*)d_in[26],
    (const float*)d_in[27], (const float*)d_in[28], (const float*)d_in[29], (const float*)d_in[30]);
  wtl_fwd<<<2048, 256, 0, stream>>>(x, ws, (float*)d_out);
}